// Round 14
// baseline (926.674 us; speedup 1.0000x reference)
//
#include <hip/hip_runtime.h>
#include <math.h>

namespace {

constexpr int NB    = 128;
constexpr int NPER  = 205;
constexpr int H     = 200;
constexpr int EMBD  = 768;
constexpr int SEQ   = 512;
constexpr int NLAY  = 6;
constexpr int NNODE = NB * NPER;   // 26240
constexpr int NEDGE = 209920;
constexpr int KP    = 448;         // packed K: agg [0,224), h [224,448)
constexpr int HOFF  = 224;

typedef __bf16 bf16;
typedef _Float16 f16;
typedef __attribute__((ext_vector_type(8))) __bf16 bf16x8;
typedef __attribute__((ext_vector_type(8))) _Float16 f16x8;
typedef __attribute__((ext_vector_type(4))) float f32x4;
typedef unsigned short ushort8 __attribute__((ext_vector_type(8)));
typedef float float4v __attribute__((ext_vector_type(4)));

__device__ __forceinline__ float sigm(float x) { return 1.0f / (1.0f + expf(-x)); }

__device__ __forceinline__ unsigned short f2bf(float x) {
    unsigned int u = __float_as_uint(x);
    unsigned int r = (u + 0x7fffu + ((u >> 16) & 1u)) >> 16;
    return (unsigned short)r;
}
__device__ __forceinline__ unsigned short f2h(float x) {
    union { f16 h; unsigned short u; } c;
    c.h = (f16)x;
    return c.u;
}
__device__ __forceinline__ float h2f(unsigned short u) {
    union { unsigned short u; f16 h; } c;
    c.u = u;
    return (float)c.h;
}

// pair-packed swizzled LDS unit index for 64B logical rows (32 cin elems)
__device__ __forceinline__ int pk_unit(int row, int s) {
    int q = row >> 1;
    return q * 8 + ((((row & 1) << 2) | s) ^ (q & 7));
}

// ================= fp16 MFMA GEMM, 64x64 wave tile, 128x128 block, z-batched (prep) =================
template<bool BIAS, bool OUTF16>
__global__ __launch_bounds__(256, 4)
void gemm_w64(const unsigned short* __restrict__ A, int lda,
              const unsigned short* __restrict__ B, size_t strideBz,
              const float* __restrict__ bias, int Mreal, int Nreal,
              float* __restrict__ Cf, unsigned short* __restrict__ Ch, size_t strideCz,
              int ldc, int Kpad)
{
    __shared__ unsigned short As[128 * 64];
    __shared__ unsigned short Bs[128 * 64];

    const int p0 = blockIdx.x * 128;
    const int o0 = blockIdx.y * 128;
    const unsigned short* Bz = B + (size_t)blockIdx.z * strideBz;
    const int tid = threadIdx.x, lane = tid & 63, wid = tid >> 6;
    const int wm = wid >> 1, wn = wid & 1;
    const int lrow = lane & 15, lk = lane >> 4;

    f32x4 acc[4][4];
    #pragma unroll
    for (int i = 0; i < 4; ++i)
        #pragma unroll
        for (int j = 0; j < 4; ++j) acc[i][j] = (f32x4){0.f, 0.f, 0.f, 0.f};

    for (int c0 = 0; c0 < Kpad; c0 += 64) {
        __syncthreads();
        for (int i = wid; i < 32; i += 4) {
            if (i < 16) {
                int u = i * 64 + lane;
                int row = u >> 3, slot = u & 7;
                int ss = slot ^ (row & 7);
                const unsigned short* sA = A + (size_t)(p0 + row) * lda + c0 + ss * 8;
                __builtin_amdgcn_global_load_lds(
                    (const __attribute__((address_space(1))) void*)sA,
                    (__attribute__((address_space(3))) void*)(As + i * 512), 16, 0, 0);
            } else {
                int i2 = i - 16;
                int u = i2 * 64 + lane;
                int row = u >> 3, slot = u & 7;
                int ss = slot ^ (row & 7);
                const unsigned short* sB = Bz + (size_t)(o0 + row) * Kpad + c0 + ss * 8;
                __builtin_amdgcn_global_load_lds(
                    (const __attribute__((address_space(1))) void*)sB,
                    (__attribute__((address_space(3))) void*)(Bs + i2 * 512), 16, 0, 0);
            }
        }
        __syncthreads();
        #pragma unroll
        for (int hf = 0; hf < 2; ++hf) {
            f16x8 vb[4];
            #pragma unroll
            for (int fn = 0; fn < 4; ++fn) {
                int r = wn * 64 + fn * 16 + lrow;
                int sl = (hf * 4 + lk) ^ (r & 7);
                vb[fn] = *reinterpret_cast<const f16x8*>(&Bs[r * 64 + sl * 8]);
            }
            #pragma unroll
            for (int fm = 0; fm < 4; ++fm) {
                int r = wm * 64 + fm * 16 + lrow;
                int sl = (hf * 4 + lk) ^ (r & 7);
                f16x8 va = *reinterpret_cast<const f16x8*>(&As[r * 64 + sl * 8]);
                #pragma unroll
                for (int fn = 0; fn < 4; ++fn)
                    acc[fm][fn] = __builtin_amdgcn_mfma_f32_16x16x32_f16(va, vb[fn], acc[fm][fn], 0, 0, 0);
            }
        }
    }
    #pragma unroll
    for (int fn = 0; fn < 4; ++fn) {
        int o = o0 + wn * 64 + fn * 16 + lrow;
        if (o >= Nreal) continue;
        float bv = BIAS ? bias[o] : 0.0f;
        #pragma unroll
        for (int fm = 0; fm < 4; ++fm) {
            #pragma unroll
            for (int i = 0; i < 4; ++i) {
                int p = p0 + wm * 64 + fm * 16 + lk * 4 + i;
                if (p >= Mreal) continue;
                float v = acc[fm][fn][i] + bv;
                if (OUTF16) Ch[(size_t)blockIdx.z * strideCz + (size_t)p * ldc + o] = f2h(v);
                else        Cf[(size_t)blockIdx.z * strideCz + (size_t)p * ldc + o] = v;
            }
        }
    }
}

// ================= fused gate-GEMM + GRU epilogue (K=448) =================
__global__ __launch_bounds__(256, 2)
void gemm_gru(const unsigned short* __restrict__ A,
              const unsigned short* __restrict__ B,
              const float* __restrict__ bb,
              unsigned short* __restrict__ Hn)
{
    __shared__ unsigned short As[2][128 * 64];
    __shared__ unsigned short Bs[2][128 * 64];

    const int p0 = blockIdx.x * 128;
    const int o0 = blockIdx.y * 128;
    const int tid = threadIdx.x, lane = tid & 63, wid = tid >> 6;
    const int wm = wid >> 1, wn = wid & 1;
    const int lrow = lane & 15, lk = lane >> 4;

    auto stage = [&](int bs, int c0) {
        for (int i = wid; i < 32; i += 4) {
            if (i < 16) {
                int u = i * 64 + lane;
                int row = u >> 3, slot = u & 7;
                int ss = slot ^ (row & 7);
                const unsigned short* sA = A + (size_t)(p0 + row) * KP + c0 + ss * 8;
                __builtin_amdgcn_global_load_lds(
                    (const __attribute__((address_space(1))) void*)sA,
                    (__attribute__((address_space(3))) void*)(&As[bs][i * 512]), 16, 0, 0);
            } else {
                int i2 = i - 16;
                int u = i2 * 64 + lane;
                int row = u >> 3, slot = u & 7;
                int ss = slot ^ (row & 7);
                const unsigned short* sB = B + (size_t)(o0 + row) * KP + c0 + ss * 8;
                __builtin_amdgcn_global_load_lds(
                    (const __attribute__((address_space(1))) void*)sB,
                    (__attribute__((address_space(3))) void*)(&Bs[bs][i2 * 512]), 16, 0, 0);
            }
        }
    };

    f32x4 acc[4][4];
    #pragma unroll
    for (int i = 0; i < 4; ++i)
        #pragma unroll
        for (int j = 0; j < 4; ++j) acc[i][j] = (f32x4){0.f, 0.f, 0.f, 0.f};

    stage(0, 0);
    __syncthreads();
    int bs = 0;
    constexpr int NIT = KP / 64;   // 7
    for (int t = 0; t < NIT; ++t) {
        if (t + 1 < NIT) stage(bs ^ 1, (t + 1) * 64);
        const unsigned short* Asc = As[bs];
        const unsigned short* Bsc = Bs[bs];
        #pragma unroll
        for (int hf = 0; hf < 2; ++hf) {
            f16x8 vb[4];
            #pragma unroll
            for (int fn = 0; fn < 4; ++fn) {
                int r = wn * 64 + fn * 16 + lrow;
                int sl = (hf * 4 + lk) ^ (r & 7);
                vb[fn] = *reinterpret_cast<const f16x8*>(&Bsc[r * 64 + sl * 8]);
            }
            #pragma unroll
            for (int fm = 0; fm < 4; ++fm) {
                int r = wm * 64 + fm * 16 + lrow;
                int sl = (hf * 4 + lk) ^ (r & 7);
                f16x8 va = *reinterpret_cast<const f16x8*>(&Asc[r * 64 + sl * 8]);
                #pragma unroll
                for (int fn = 0; fn < 4; ++fn)
                    acc[fm][fn] = __builtin_amdgcn_mfma_f32_16x16x32_f16(va, vb[fn], acc[fm][fn], 0, 0, 0);
            }
        }
        __syncthreads();
        bs ^= 1;
    }

    // ---- GRU epilogue ----
    const int colbase = o0 + wn * 64;
    const int c = (colbase >> 2) + lrow;     // channel
    float b0 = bb[colbase + 0 * 16 + lrow];
    float b1 = bb[colbase + 1 * 16 + lrow];
    float b2 = bb[colbase + 2 * 16 + lrow];
    float b3 = bb[colbase + 3 * 16 + lrow];
    #pragma unroll
    for (int fm = 0; fm < 4; ++fm) {
        #pragma unroll
        for (int i = 0; i < 4; ++i) {
            int p = p0 + wm * 64 + fm * 16 + lk * 4 + i;
            if (c < H) {
                size_t hidx = (size_t)p * KP + HOFF + c;
                float r = sigm(acc[fm][0][i] + b0);
                float z = sigm(acc[fm][1][i] + b1);
                float nn = tanhf((acc[fm][2][i] + b2) + r * (acc[fm][3][i] + b3));
                float ho = h2f(A[hidx]);
                Hn[hidx] = f2h((1.0f - z) * nn + z * ho);
            }
        }
    }
}

// ================= bf16 conv, 256x128 block, 4 waves of 128x64, BK=32, single buffer =================
// Wave tile 128(p) x 64(o): fm=8, fn=4 -> 12 LDS reads per 32 MFMAs (0.375 KB/MFMA vs 0.5 before).
template<int K, int CINP, int LIN, int LOUT>
__global__ __launch_bounds__(256, 2)
void conv_w128(const unsigned short* __restrict__ E, const unsigned short* __restrict__ WT,
               const float* __restrict__ bias, int COUT,
               float* __restrict__ feats, int foff)
{
    constexpr int AROWS  = 272;
    constexpr int AINSTR = AROWS * 4 / 64;      // 17
    constexpr int BINSTR = K * 128 * 4 / 64;    // K*8
    __shared__ unsigned short As[AROWS * 32];
    __shared__ unsigned short Bs[K * 128 * 32];

    const int p0 = blockIdx.x * 256;
    const int o0 = blockIdx.y * 128;
    const int b  = blockIdx.z;
    const int tid = threadIdx.x, lane = tid & 63, wid = tid >> 6;
    const int wm = wid >> 1, wn = wid & 1;      // 2x2 wave grid, wave tile 128x64
    const int lrow = lane & 15, lk = lane >> 4;

    const unsigned short* Eb = E + (size_t)b * LIN * CINP;

    f32x4 acc[8][4];
    #pragma unroll
    for (int i = 0; i < 8; ++i)
        #pragma unroll
        for (int j = 0; j < 4; ++j) acc[i][j] = (f32x4){0.f, 0.f, 0.f, 0.f};

    for (int c0 = 0; c0 < CINP; c0 += 32) {
        __syncthreads();
        for (int i = wid; i < AINSTR + BINSTR; i += 4) {
            if (i < AINSTR) {
                int u = i * 64 + lane;
                int q = u >> 3, cs = u & 7;
                int bsw = cs ^ (q & 7);
                int row = q * 2 + (bsw >> 2), s = bsw & 3;
                int srow = p0 + row; if (srow > LIN - 1) srow = LIN - 1;
                const unsigned short* src = Eb + (size_t)srow * CINP + c0 + s * 8;
                __builtin_amdgcn_global_load_lds(
                    (const __attribute__((address_space(1))) void*)src,
                    (__attribute__((address_space(3))) void*)(As + i * 512), 16, 0, 0);
            } else {
                int i2 = i - AINSTR;
                int u = i2 * 64 + lane;
                int q = u >> 3, cs = u & 7;
                int bsw = cs ^ (q & 7);
                int R = q * 2 + (bsw >> 2), s = bsw & 3;
                int k = R >> 7, r = R & 127;
                const unsigned short* src = WT + ((size_t)k * 256 + o0 + r) * CINP + c0 + s * 8;
                __builtin_amdgcn_global_load_lds(
                    (const __attribute__((address_space(1))) void*)src,
                    (__attribute__((address_space(3))) void*)(Bs + i2 * 512), 16, 0, 0);
            }
        }
        __syncthreads();
        #pragma unroll
        for (int k = 0; k < K; ++k) {
            bf16x8 vb[4];
            #pragma unroll
            for (int fn = 0; fn < 4; ++fn) {
                int R = k * 128 + wn * 64 + fn * 16 + lrow;
                vb[fn] = *reinterpret_cast<const bf16x8*>(&Bs[pk_unit(R, lk) * 8]);
            }
            #pragma unroll
            for (int fm = 0; fm < 8; ++fm) {
                int r = wm * 128 + fm * 16 + lrow + k;
                bf16x8 va = *reinterpret_cast<const bf16x8*>(&As[pk_unit(r, lk) * 8]);
                #pragma unroll
                for (int fn = 0; fn < 4; ++fn)
                    acc[fm][fn] = __builtin_amdgcn_mfma_f32_16x16x32_bf16(va, vb[fn], acc[fm][fn], 0, 0, 0);
            }
        }
    }
    #pragma unroll
    for (int fn = 0; fn < 4; ++fn) {
        int o = o0 + wn * 64 + fn * 16 + lrow;
        float mx = 0.0f;   // relu floor
        if (o < COUT) {
            float bv = bias[o];
            #pragma unroll
            for (int fm = 0; fm < 8; ++fm)
                #pragma unroll
                for (int i = 0; i < 4; ++i) {
                    int p = p0 + wm * 128 + fm * 16 + lk * 4 + i;
                    if (p < LOUT) mx = fmaxf(mx, acc[fm][fn][i] + bv);
                }
        }
        mx = fmaxf(mx, __shfl_xor(mx, 16));
        mx = fmaxf(mx, __shfl_xor(mx, 32));
        if (lane < 16 && o < COUT)
            atomicMax((int*)&feats[(size_t)b * 800 + foff + o], __float_as_int(mx));
    }
}

// ================= CSR build =================
__global__ void hist_kernel(const int* __restrict__ dst, int* __restrict__ deg)
{
    int e = blockIdx.x * 256 + threadIdx.x;
    if (e < NEDGE) atomicAdd(&deg[dst[e]], 1);
}

__global__ void scan_kernel(const int* __restrict__ deg, int* __restrict__ off, int* __restrict__ cur)
{
    __shared__ int part[1024];
    const int tid = threadIdx.x;
    const int CH = (NNODE + 1023) / 1024;
    int base = tid * CH;
    int s = 0;
    for (int i = 0; i < CH; ++i) { int idx = base + i; s += (idx < NNODE ? deg[idx] : 0); }
    part[tid] = s;
    __syncthreads();
    for (int d = 1; d < 1024; d <<= 1) {
        int v = (tid >= d) ? part[tid - d] : 0;
        __syncthreads();
        part[tid] += v;
        __syncthreads();
    }
    int run = tid ? part[tid - 1] : 0;
    for (int i = 0; i < CH; ++i) {
        int idx = base + i;
        if (idx < NNODE) { off[idx] = run; cur[idx] = run; run += deg[idx]; }
    }
    if (tid == 1023) off[NNODE] = run;
}

__global__ void fill_kernel(const int* __restrict__ src, const int* __restrict__ dst,
                            int* __restrict__ cur, int* __restrict__ eidx)
{
    int e = blockIdx.x * 256 + threadIdx.x;
    if (e >= NEDGE) return;
    int d = dst[e];
    int pos = atomicAdd(&cur[d], 1);
    eidx[pos] = src[e];
}

// ================= per-layer kernels =================
__global__ void gather_h2(const int* __restrict__ off, const int* __restrict__ eidx,
                          unsigned short* __restrict__ acat)
{
    int t = blockIdx.x * 256 + threadIdx.x;
    if (t >= NNODE * 32) return;
    int c8 = t & 31, n = t >> 5;
    if (c8 >= 25) return;
    const size_t cb = (size_t)c8 * 8;
    float s[8] = {0.f, 0.f, 0.f, 0.f, 0.f, 0.f, 0.f, 0.f};
    int beg = off[n], end = off[n + 1];
    int i = beg;
    for (; i + 4 <= end; i += 4) {
        int s0 = eidx[i], s1 = eidx[i + 1], s2 = eidx[i + 2], s3 = eidx[i + 3];
        ushort8 a = *(const ushort8*)(acat + (size_t)s0 * KP + HOFF + cb);
        ushort8 b = *(const ushort8*)(acat + (size_t)s1 * KP + HOFF + cb);
        ushort8 c = *(const ushort8*)(acat + (size_t)s2 * KP + HOFF + cb);
        ushort8 d = *(const ushort8*)(acat + (size_t)s3 * KP + HOFF + cb);
        #pragma unroll
        for (int j = 0; j < 8; ++j)
            s[j] += (h2f(a[j]) + h2f(b[j])) + (h2f(c[j]) + h2f(d[j]));
    }
    for (; i < end; ++i) {
        int sn = eidx[i];
        ushort8 hh = *(const ushort8*)(acat + (size_t)sn * KP + HOFF + cb);
        #pragma unroll
        for (int j = 0; j < 8; ++j) s[j] += h2f(hh[j]);
    }
    ushort8 o;
    #pragma unroll
    for (int j = 0; j < 8; ++j) o[j] = f2h(s[j]);
    *(ushort8*)(acat + (size_t)n * KP + cb) = o;
}

__global__ void h0_kernel(const float* __restrict__ x, unsigned short* __restrict__ acat)
{
    int t = blockIdx.x * 256 + threadIdx.x;
    if (t >= NNODE * 32) return;
    int c8 = t & 31, n = t >> 5;
    if (c8 >= 28) return;
    ushort8 o = {0,0,0,0,0,0,0,0};
    if (c8 < 25) {
        const float* src = x + (size_t)n * H + c8 * 8;
        float4v v0 = *(const float4v*)src;
        float4v v1 = *(const float4v*)(src + 4);
        o[0] = f2h(v0[0]); o[1] = f2h(v0[1]); o[2] = f2h(v0[2]); o[3] = f2h(v0[3]);
        o[4] = f2h(v1[0]); o[5] = f2h(v1[1]); o[6] = f2h(v1[2]); o[7] = f2h(v1[3]);
    }
    *(ushort8*)(acat + (size_t)n * KP + HOFF + c8 * 8) = o;
}

// ================= weight prep (gate-permuted) =================
__global__ void wih16p_prep(const float* __restrict__ wih, unsigned short* __restrict__ w16)
{
    int t = blockIdx.x * 256 + threadIdx.x;
    if (t >= 896 * 32) return;
    int c8 = t & 31, r = t >> 5;
    int g = (r >> 4) & 3;
    int c = (r >> 6) * 16 + (r & 15);
    ushort8 o = {0,0,0,0,0,0,0,0};
    if (g < 3 && c < H) {
        #pragma unroll
        for (int j = 0; j < 8; ++j) {
            int k = c8 * 8 + j;
            if (k < H) o[j] = f2h(wih[(size_t)(g * 200 + c) * H + k]);
        }
    }
    *(ushort8*)(w16 + (size_t)r * 256 + c8 * 8) = o;
}

__global__ void wl_prep(const float* __restrict__ w, unsigned short* __restrict__ wl)
{
    int t = blockIdx.x * 256 + threadIdx.x;
    if (t >= NLAY * 256 * 32) return;
    int c8 = t & 31;
    int rest = t >> 5;
    int jr = rest & 255;
    int l = rest >> 8;
    ushort8 o = {0,0,0,0,0,0,0,0};
    if (jr < H) {
        #pragma unroll
        for (int j = 0; j < 8; ++j) {
            int k = c8 * 8 + j;
            if (k < H) o[j] = f2h(w[(size_t)l * H * H + (size_t)jr * H + k]);
        }
    }
    *(ushort8*)(wl + (size_t)l * 65536 + (size_t)jr * 256 + c8 * 8) = o;
}

// right half (K-cols 224..447) of permuted Wf[l][896][448]; also permuted bias bb[896]
__global__ void wf_rightp(const float* __restrict__ whh, const float* __restrict__ bih,
                          const float* __restrict__ bhh,
                          unsigned short* __restrict__ Wf, float* __restrict__ bb)
{
    int t = blockIdx.x * 256 + threadIdx.x;
    if (t >= NLAY * 896 * 28) return;
    int c8 = t % 28;
    int rest = t / 28;
    int r = rest % 896;
    int l = rest / 896;
    int g = (r >> 4) & 3;
    int c = (r >> 6) * 16 + (r & 15);
    ushort8 o = {0,0,0,0,0,0,0,0};
    if (c < H) {
        #pragma unroll
        for (int j = 0; j < 8; ++j) {
            int kk = c8 * 8 + j;
            float v = 0.0f;
            if (kk < H) {
                if (g == 0)      v = whh[(size_t)c * H + kk];
                else if (g == 1) v = whh[(size_t)(200 + c) * H + kk];
                else if (g == 3) v = whh[(size_t)(400 + c) * H + kk];
            }
            o[j] = f2h(v);
        }
    }
    *(ushort8*)(Wf + (size_t)l * (896 * KP) + (size_t)r * KP + HOFF + c8 * 8) = o;
    if (l == 0 && c8 == 0) {
        float bv = 0.0f;
        if (c < H) {
            if (g == 0)      bv = bih[c] + bhh[c];
            else if (g == 1) bv = bih[200 + c] + bhh[200 + c];
            else if (g == 2) bv = bih[400 + c];
            else             bv = bhh[400 + c];
        }
        bb[r] = bv;
    }
}

// ================= conv-phase prep =================
__global__ void embed_bf16_kernel(const int* __restrict__ ids, const float* __restrict__ table,
                                  unsigned short* __restrict__ e)
{
    int t = blockIdx.x * 256 + threadIdx.x;
    const int total = NB * SEQ * (EMBD / 8);
    if (t >= total) return;
    int j = t % (EMBD / 8), row = t / (EMBD / 8);
    int id = ids[row];
    const float* src = table + (size_t)id * EMBD + j * 8;
    float4v v0 = *(const float4v*)src;
    float4v v1 = *(const float4v*)(src + 4);
    ushort8 o;
    o[0] = f2bf(v0[0]); o[1] = f2bf(v0[1]); o[2] = f2bf(v0[2]); o[3] = f2bf(v0[3]);
    o[4] = f2bf(v1[0]); o[5] = f2bf(v1[1]); o[6] = f2bf(v1[2]); o[7] = f2bf(v1[3]);
    *(ushort8*)(e + (size_t)row * EMBD + j * 8) = o;
}

__global__ void h_pad_from_acat(const unsigned short* __restrict__ acat,
                                unsigned short* __restrict__ e0)
{
    int t = blockIdx.x * 256 + threadIdx.x;
    const int total = NB * 208 * 32;
    if (t >= total) return;
    int c8 = t % 32, rest = t / 32;
    int r = rest % 208, b = rest / 208;
    ushort8 o = {0,0,0,0,0,0,0,0};
    if (r >= 1 && r <= 205 && c8 < 25) {
        int node = b * NPER + (r - 1);
        ushort8 hh = *(const ushort8*)(acat + (size_t)node * KP + HOFF + c8 * 8);
        #pragma unroll
        for (int j = 0; j < 8; ++j) o[j] = f2bf(h2f(hh[j]));
    }
    *(ushort8*)(e0 + ((size_t)(b * 208 + r)) * 256 + c8 * 8) = o;
}

__global__ void wconv_bf16_kernel(const float* __restrict__ w, unsigned short* __restrict__ wt,
                                  int K, int CINP, int CINR, int COUT)
{
    long long t = (long long)blockIdx.x * 256 + threadIdx.x;
    long long total = (long long)K * 256 * CINP;
    if (t >= total) return;
    int cin = (int)(t % CINP);
    long long rest = t / CINP;
    int o = (int)(rest % 256), k = (int)(rest / 256);
    float v = 0.0f;
    if (o < COUT && cin < CINR) v = w[((size_t)o * CINR + cin) * K + k];
    wt[t] = f2bf(v);
}

__global__ __launch_bounds__(256)
void fc_head(const float* __restrict__ feats,
             const float* __restrict__ w1, const float* __restrict__ b1,
             const float* __restrict__ w2, const float* __restrict__ b2,
             const float* __restrict__ w3, const float* __restrict__ b3,
             float* __restrict__ out)
{
    __shared__ float f[800];
    __shared__ float h1[256];
    __shared__ float h2[128];
    const int b = blockIdx.x, tid = threadIdx.x;
    for (int i = tid; i < 800; i += 256) f[i] = feats[(size_t)b * 800 + i];
    __syncthreads();
    {
        float acc = b1[tid];
        const float* wr = w1 + (size_t)tid * 800;
        for (int k = 0; k < 800; ++k) acc = fmaf(f[k], wr[k], acc);
        h1[tid] = fmaxf(acc, 0.0f);
    }
    __syncthreads();
    if (tid < 128) {
        float acc = b2[tid];
        const float* wr = w2 + (size_t)tid * 256;
        for (int k = 0; k < 256; ++k) acc = fmaf(h1[k], wr[k], acc);
        h2[tid] = fmaxf(acc, 0.0f);
    }
    __syncthreads();
    if (tid < 2) {
        float acc = b3[tid];
        const float* wr = w3 + (size_t)tid * 128;
        for (int k = 0; k < 128; ++k) acc = fmaf(h2[k], wr[k], acc);
        out[(size_t)b * 2 + tid] = acc;
    }
}

} // namespace

extern "C" void kernel_launch(void* const* d_in, const int* in_sizes, int n_in,
                              void* d_out, int out_size, void* d_ws, size_t ws_size,
                              hipStream_t stream)
{
    const float* x         = (const float*)d_in[0];
    const int*   edge      = (const int*)d_in[1];
    const int*   input_ids = (const int*)d_in[2];
    const float* table     = (const float*)d_in[3];
    const float* ggc_w     = (const float*)d_in[4];
    const float* wih       = (const float*)d_in[5];
    const float* whh       = (const float*)d_in[6];
    const float* bih       = (const float*)d_in[7];
    const float* bhh       = (const float*)d_in[8];
    const float* c0w = (const float*)d_in[9];  const float* c0b = (const float*)d_in[10];
    const float* c1w = (const float*)d_in[11]; const float* c1b = (const float*)d_in[12];
    const float* c2w = (const float*)d_in[13]; const float* c2b = (const float*)d_in[14];
    const float* c3w = (const float*)d_in[15]; const float* c3b = (const float*)d_in[16];
    const float* f1w = (const float*)d_in[17]; const float* f1b = (const float*)d_in[18];
    const float* f2w = (const float*)d_in[19]; const float* f2b = (const float*)d_in[20];
    const float* f3w = (const float*)d_in[21]; const float* f3b = (const float*)d_in[22];
    float* out = (float*)d_out;

    // ---- workspace layout (float-slot offsets) ----
    float* ws = (float*)d_ws;
    unsigned short* acat_a = (unsigned short*)(ws + 0);          // 26240*448 ush
    unsigned short* acat_b = (unsigned short*)(ws + 5877760);    // 26240*448 ush
    unsigned short* Wf     = (unsigned short*)(ws + 11755520);   // 6*896*448 ush
    unsigned short* wl16   = (unsigned short*)(ws + 12959744);   // 6*256*256 ush
    unsigned short* wih16p = (unsigned short*)(ws + 13156352);   // 896*256 ush
    float* b_big = ws + 13271040;                                // 896
    int* deg  = (int*)(ws + 13271936);                           // 26240
    int* off  = (int*)(ws + 13298176);                           // 26241
    int* cur  = (int*)(ws + 13324417);                           // 26241
    int* eidx = (int*)(ws + 13350658);                           // 209920
    // conv-phase aliases (all GGC buffers dead by then):
    unsigned short* e_bf16 = (unsigned short*)(ws + 0);          // 128*512*768 ush
    unsigned short* e0     = (unsigned short*)(ws + 25165824);   // 128*208*256 ush
    unsigned short* wt0    = (unsigned short*)(ws + 28600000);
    unsigned short* wt1    = wt0 + (size_t)3 * 256 * 256;
    unsigned short* wt2    = wt1 + (size_t)3 * 256 * EMBD;
    unsigned short* wt3    = wt2 + (size_t)4 * 256 * EMBD;
    float* feats = ws + 29900000;                                // 128*800

    const int* srcp = edge;
    const int* dstp = edge + NEDGE;

    dim3 blk(256);

    // ---- one-time prep ----
    hipMemsetAsync(deg, 0, sizeof(int) * NNODE, stream);
    hist_kernel<<<dim3((NEDGE + 255) / 256), blk, 0, stream>>>(dstp, deg);
    scan_kernel<<<dim3(1), dim3(1024), 0, stream>>>(deg, off, cur);
    fill_kernel<<<dim3((NEDGE + 255) / 256), blk, 0, stream>>>(srcp, dstp, cur, eidx);
    h0_kernel<<<dim3((NNODE * 32 + 255) / 256), blk, 0, stream>>>(x, acat_a);
    wih16p_prep<<<dim3((896 * 32 + 255) / 256), blk, 0, stream>>>(wih, wih16p);
    wl_prep<<<dim3((NLAY * 256 * 32 + 255) / 256), blk, 0, stream>>>(ggc_w, wl16);
    hipMemsetAsync(Wf, 0, (size_t)NLAY * 896 * KP * 2, stream);
    wf_rightp<<<dim3((NLAY * 896 * 28 + 255) / 256), blk, 0, stream>>>(whh, bih, bhh, Wf, b_big);
    // Wf left (K-cols 0..199) = wih_perm @ W_l^T, batched over layers via z
    gemm_w64<false, true><<<dim3(7, 2, NLAY), blk, 0, stream>>>(
        wih16p, 256, wl16, (size_t)256 * 256, nullptr, 896, 200,
        nullptr, Wf, (size_t)896 * KP, KP, 256);

    // ---- GGC layers: gather + fused gate-GEMM/GRU (ping-pong acat) ----
    unsigned short* bufs[2] = { acat_a, acat_b };
    for (int l = 0; l < NLAY; ++l) {
        unsigned short* curb = bufs[l & 1];
        unsigned short* nxtb = bufs[(l + 1) & 1];
        gather_h2<<<dim3((NNODE * 32 + 255) / 256), blk, 0, stream>>>(off, eidx, curb);
        gemm_gru<<<dim3(NNODE / 128, 7), blk, 0, stream>>>(
            curb, Wf + (size_t)l * (896 * KP), b_big, nxtb);
    }
    // after 6 layers, h lives in bufs[0] = acat_a

    // ---- conv phase ----
    h_pad_from_acat<<<dim3((NB * 208 * 32 + 255) / 256), blk, 0, stream>>>(acat_a, e0);
    embed_bf16_kernel<<<dim3(NB * SEQ * (EMBD / 8) / 256), blk, 0, stream>>>(input_ids, table, e_bf16);
    wconv_bf16_kernel<<<dim3((3 * 256 * 256 + 255) / 256), blk, 0, stream>>>(c0w, wt0, 3, 256, 200, 200);
    wconv_bf16_kernel<<<dim3((3 * 256 * EMBD + 255) / 256), blk, 0, stream>>>(c1w, wt1, 3, EMBD, EMBD, 200);
    wconv_bf16_kernel<<<dim3((4 * 256 * EMBD + 255) / 256), blk, 0, stream>>>(c2w, wt2, 4, EMBD, EMBD, 200);
    wconv_bf16_kernel<<<dim3((5 * 256 * EMBD + 255) / 256), blk, 0, stream>>>(c3w, wt3, 5, EMBD, EMBD, 200);

    hipMemsetAsync(feats, 0, sizeof(float) * NB * 800, stream);
    conv_w128<3, 256, 208, 205><<<dim3(1, 2, NB), blk, 0, stream>>>(e0, wt0, c0b, 200, feats, 0);
    conv_w128<3, EMBD, SEQ, 510><<<dim3(2, 2, NB), blk, 0, stream>>>(e_bf16, wt1, c1b, 200, feats, 200);
    conv_w128<4, EMBD, SEQ, 509><<<dim3(2, 2, NB), blk, 0, stream>>>(e_bf16, wt2, c2b, 200, feats, 400);
    conv_w128<5, EMBD, SEQ, 508><<<dim3(2, 2, NB), blk, 0, stream>>>(e_bf16, wt3, c3b, 200, feats, 600);

    fc_head<<<dim3(NB), blk, 0, stream>>>(feats, f1w, f1b, f2w, f2b, f3w, f3b, out);
}

// Round 15
// 904.825 us; speedup vs baseline: 1.0241x; 1.0241x over previous
//
#include <hip/hip_runtime.h>
#include <math.h>

namespace {

constexpr int NB    = 128;
constexpr int NPER  = 205;
constexpr int H     = 200;
constexpr int EMBD  = 768;
constexpr int SEQ   = 512;
constexpr int NLAY  = 6;
constexpr int NNODE = NB * NPER;   // 26240
constexpr int NEDGE = 209920;
constexpr int KP    = 448;         // packed K: agg [0,224), h [224,448)
constexpr int HOFF  = 224;

typedef __bf16 bf16;
typedef _Float16 f16;
typedef __attribute__((ext_vector_type(8))) __bf16 bf16x8;
typedef __attribute__((ext_vector_type(8))) _Float16 f16x8;
typedef __attribute__((ext_vector_type(4))) float f32x4;
typedef unsigned short ushort8 __attribute__((ext_vector_type(8)));
typedef float float4v __attribute__((ext_vector_type(4)));

__device__ __forceinline__ float sigm(float x) { return 1.0f / (1.0f + expf(-x)); }

__device__ __forceinline__ unsigned short f2bf(float x) {
    unsigned int u = __float_as_uint(x);
    unsigned int r = (u + 0x7fffu + ((u >> 16) & 1u)) >> 16;
    return (unsigned short)r;
}
__device__ __forceinline__ unsigned short f2h(float x) {
    union { f16 h; unsigned short u; } c;
    c.h = (f16)x;
    return c.u;
}
__device__ __forceinline__ float h2f(unsigned short u) {
    union { unsigned short u; f16 h; } c;
    c.u = u;
    return (float)c.h;
}

// pair-packed swizzled LDS unit index for 64B logical rows (32 cin elems)
__device__ __forceinline__ int pk_unit(int row, int s) {
    int q = row >> 1;
    return q * 8 + ((((row & 1) << 2) | s) ^ (q & 7));
}

// ================= fp16 MFMA GEMM, 64x64 wave tile, 128x128 block, z-batched (prep) =================
template<bool BIAS, bool OUTF16>
__global__ __launch_bounds__(256, 4)
void gemm_w64(const unsigned short* __restrict__ A, int lda,
              const unsigned short* __restrict__ B, size_t strideBz,
              const float* __restrict__ bias, int Mreal, int Nreal,
              float* __restrict__ Cf, unsigned short* __restrict__ Ch, size_t strideCz,
              int ldc, int Kpad)
{
    __shared__ unsigned short As[128 * 64];
    __shared__ unsigned short Bs[128 * 64];

    const int p0 = blockIdx.x * 128;
    const int o0 = blockIdx.y * 128;
    const unsigned short* Bz = B + (size_t)blockIdx.z * strideBz;
    const int tid = threadIdx.x, lane = tid & 63, wid = tid >> 6;
    const int wm = wid >> 1, wn = wid & 1;
    const int lrow = lane & 15, lk = lane >> 4;

    f32x4 acc[4][4];
    #pragma unroll
    for (int i = 0; i < 4; ++i)
        #pragma unroll
        for (int j = 0; j < 4; ++j) acc[i][j] = (f32x4){0.f, 0.f, 0.f, 0.f};

    for (int c0 = 0; c0 < Kpad; c0 += 64) {
        __syncthreads();
        for (int i = wid; i < 32; i += 4) {
            if (i < 16) {
                int u = i * 64 + lane;
                int row = u >> 3, slot = u & 7;
                int ss = slot ^ (row & 7);
                const unsigned short* sA = A + (size_t)(p0 + row) * lda + c0 + ss * 8;
                __builtin_amdgcn_global_load_lds(
                    (const __attribute__((address_space(1))) void*)sA,
                    (__attribute__((address_space(3))) void*)(As + i * 512), 16, 0, 0);
            } else {
                int i2 = i - 16;
                int u = i2 * 64 + lane;
                int row = u >> 3, slot = u & 7;
                int ss = slot ^ (row & 7);
                const unsigned short* sB = Bz + (size_t)(o0 + row) * Kpad + c0 + ss * 8;
                __builtin_amdgcn_global_load_lds(
                    (const __attribute__((address_space(1))) void*)sB,
                    (__attribute__((address_space(3))) void*)(Bs + i2 * 512), 16, 0, 0);
            }
        }
        __syncthreads();
        #pragma unroll
        for (int hf = 0; hf < 2; ++hf) {
            f16x8 vb[4];
            #pragma unroll
            for (int fn = 0; fn < 4; ++fn) {
                int r = wn * 64 + fn * 16 + lrow;
                int sl = (hf * 4 + lk) ^ (r & 7);
                vb[fn] = *reinterpret_cast<const f16x8*>(&Bs[r * 64 + sl * 8]);
            }
            #pragma unroll
            for (int fm = 0; fm < 4; ++fm) {
                int r = wm * 64 + fm * 16 + lrow;
                int sl = (hf * 4 + lk) ^ (r & 7);
                f16x8 va = *reinterpret_cast<const f16x8*>(&As[r * 64 + sl * 8]);
                #pragma unroll
                for (int fn = 0; fn < 4; ++fn)
                    acc[fm][fn] = __builtin_amdgcn_mfma_f32_16x16x32_f16(va, vb[fn], acc[fm][fn], 0, 0, 0);
            }
        }
    }
    #pragma unroll
    for (int fn = 0; fn < 4; ++fn) {
        int o = o0 + wn * 64 + fn * 16 + lrow;
        if (o >= Nreal) continue;
        float bv = BIAS ? bias[o] : 0.0f;
        #pragma unroll
        for (int fm = 0; fm < 4; ++fm) {
            #pragma unroll
            for (int i = 0; i < 4; ++i) {
                int p = p0 + wm * 64 + fm * 16 + lk * 4 + i;
                if (p >= Mreal) continue;
                float v = acc[fm][fn][i] + bv;
                if (OUTF16) Ch[(size_t)blockIdx.z * strideCz + (size_t)p * ldc + o] = f2h(v);
                else        Cf[(size_t)blockIdx.z * strideCz + (size_t)p * ldc + o] = v;
            }
        }
    }
}

// ================= fused gate-GEMM + GRU epilogue (K=448) =================
__global__ __launch_bounds__(256, 2)
void gemm_gru(const unsigned short* __restrict__ A,
              const unsigned short* __restrict__ B,
              const float* __restrict__ bb,
              unsigned short* __restrict__ Hn)
{
    __shared__ unsigned short As[2][128 * 64];
    __shared__ unsigned short Bs[2][128 * 64];

    const int p0 = blockIdx.x * 128;
    const int o0 = blockIdx.y * 128;
    const int tid = threadIdx.x, lane = tid & 63, wid = tid >> 6;
    const int wm = wid >> 1, wn = wid & 1;
    const int lrow = lane & 15, lk = lane >> 4;

    auto stage = [&](int bs, int c0) {
        for (int i = wid; i < 32; i += 4) {
            if (i < 16) {
                int u = i * 64 + lane;
                int row = u >> 3, slot = u & 7;
                int ss = slot ^ (row & 7);
                const unsigned short* sA = A + (size_t)(p0 + row) * KP + c0 + ss * 8;
                __builtin_amdgcn_global_load_lds(
                    (const __attribute__((address_space(1))) void*)sA,
                    (__attribute__((address_space(3))) void*)(&As[bs][i * 512]), 16, 0, 0);
            } else {
                int i2 = i - 16;
                int u = i2 * 64 + lane;
                int row = u >> 3, slot = u & 7;
                int ss = slot ^ (row & 7);
                const unsigned short* sB = B + (size_t)(o0 + row) * KP + c0 + ss * 8;
                __builtin_amdgcn_global_load_lds(
                    (const __attribute__((address_space(1))) void*)sB,
                    (__attribute__((address_space(3))) void*)(&Bs[bs][i2 * 512]), 16, 0, 0);
            }
        }
    };

    f32x4 acc[4][4];
    #pragma unroll
    for (int i = 0; i < 4; ++i)
        #pragma unroll
        for (int j = 0; j < 4; ++j) acc[i][j] = (f32x4){0.f, 0.f, 0.f, 0.f};

    stage(0, 0);
    __syncthreads();
    int bs = 0;
    constexpr int NIT = KP / 64;   // 7
    for (int t = 0; t < NIT; ++t) {
        if (t + 1 < NIT) stage(bs ^ 1, (t + 1) * 64);
        const unsigned short* Asc = As[bs];
        const unsigned short* Bsc = Bs[bs];
        #pragma unroll
        for (int hf = 0; hf < 2; ++hf) {
            f16x8 vb[4];
            #pragma unroll
            for (int fn = 0; fn < 4; ++fn) {
                int r = wn * 64 + fn * 16 + lrow;
                int sl = (hf * 4 + lk) ^ (r & 7);
                vb[fn] = *reinterpret_cast<const f16x8*>(&Bsc[r * 64 + sl * 8]);
            }
            #pragma unroll
            for (int fm = 0; fm < 4; ++fm) {
                int r = wm * 64 + fm * 16 + lrow;
                int sl = (hf * 4 + lk) ^ (r & 7);
                f16x8 va = *reinterpret_cast<const f16x8*>(&Asc[r * 64 + sl * 8]);
                #pragma unroll
                for (int fn = 0; fn < 4; ++fn)
                    acc[fm][fn] = __builtin_amdgcn_mfma_f32_16x16x32_f16(va, vb[fn], acc[fm][fn], 0, 0, 0);
            }
        }
        __syncthreads();
        bs ^= 1;
    }

    // ---- GRU epilogue ----
    const int colbase = o0 + wn * 64;
    const int c = (colbase >> 2) + lrow;     // channel
    float b0 = bb[colbase + 0 * 16 + lrow];
    float b1 = bb[colbase + 1 * 16 + lrow];
    float b2 = bb[colbase + 2 * 16 + lrow];
    float b3 = bb[colbase + 3 * 16 + lrow];
    #pragma unroll
    for (int fm = 0; fm < 4; ++fm) {
        #pragma unroll
        for (int i = 0; i < 4; ++i) {
            int p = p0 + wm * 64 + fm * 16 + lk * 4 + i;
            if (c < H) {
                size_t hidx = (size_t)p * KP + HOFF + c;
                float r = sigm(acc[fm][0][i] + b0);
                float z = sigm(acc[fm][1][i] + b1);
                float nn = tanhf((acc[fm][2][i] + b2) + r * (acc[fm][3][i] + b3));
                float ho = h2f(A[hidx]);
                Hn[hidx] = f2h((1.0f - z) * nn + z * ho);
            }
        }
    }
}

// ================= bf16 conv, 256x128 block, 8 waves, BK=32, single buffer (verified optimum) =================
template<int K, int CINP, int LIN, int LOUT>
__global__ __launch_bounds__(512, 4)
void conv_w64(const unsigned short* __restrict__ E, const unsigned short* __restrict__ WT,
              const float* __restrict__ bias, int COUT,
              float* __restrict__ feats, int foff)
{
    constexpr int AROWS  = 272;
    constexpr int AINSTR = AROWS * 4 / 64;      // 17
    constexpr int BINSTR = K * 128 * 4 / 64;    // K*8
    __shared__ unsigned short As[AROWS * 32];
    __shared__ unsigned short Bs[K * 128 * 32];

    const int p0 = blockIdx.x * 256;
    const int o0 = blockIdx.y * 128;
    const int b  = blockIdx.z;
    const int tid = threadIdx.x, lane = tid & 63, wid = tid >> 6;
    const int wm = wid >> 1, wn = wid & 1;
    const int lrow = lane & 15, lk = lane >> 4;

    const unsigned short* Eb = E + (size_t)b * LIN * CINP;

    f32x4 acc[4][4];
    #pragma unroll
    for (int i = 0; i < 4; ++i)
        #pragma unroll
        for (int j = 0; j < 4; ++j) acc[i][j] = (f32x4){0.f, 0.f, 0.f, 0.f};

    for (int c0 = 0; c0 < CINP; c0 += 32) {
        __syncthreads();
        for (int i = wid; i < AINSTR + BINSTR; i += 8) {
            if (i < AINSTR) {
                int u = i * 64 + lane;
                int q = u >> 3, cs = u & 7;
                int bsw = cs ^ (q & 7);
                int row = q * 2 + (bsw >> 2), s = bsw & 3;
                int srow = p0 + row; if (srow > LIN - 1) srow = LIN - 1;
                const unsigned short* src = Eb + (size_t)srow * CINP + c0 + s * 8;
                __builtin_amdgcn_global_load_lds(
                    (const __attribute__((address_space(1))) void*)src,
                    (__attribute__((address_space(3))) void*)(As + i * 512), 16, 0, 0);
            } else {
                int i2 = i - AINSTR;
                int u = i2 * 64 + lane;
                int q = u >> 3, cs = u & 7;
                int bsw = cs ^ (q & 7);
                int R = q * 2 + (bsw >> 2), s = bsw & 3;
                int k = R >> 7, r = R & 127;
                const unsigned short* src = WT + ((size_t)k * 256 + o0 + r) * CINP + c0 + s * 8;
                __builtin_amdgcn_global_load_lds(
                    (const __attribute__((address_space(1))) void*)src,
                    (__attribute__((address_space(3))) void*)(Bs + i2 * 512), 16, 0, 0);
            }
        }
        __syncthreads();
        #pragma unroll
        for (int k = 0; k < K; ++k) {
            bf16x8 vb[4];
            #pragma unroll
            for (int fn = 0; fn < 4; ++fn) {
                int R = k * 128 + wn * 64 + fn * 16 + lrow;
                vb[fn] = *reinterpret_cast<const bf16x8*>(&Bs[pk_unit(R, lk) * 8]);
            }
            #pragma unroll
            for (int fm = 0; fm < 4; ++fm) {
                int r = wm * 64 + fm * 16 + lrow + k;
                bf16x8 va = *reinterpret_cast<const bf16x8*>(&As[pk_unit(r, lk) * 8]);
                #pragma unroll
                for (int fn = 0; fn < 4; ++fn)
                    acc[fm][fn] = __builtin_amdgcn_mfma_f32_16x16x32_bf16(va, vb[fn], acc[fm][fn], 0, 0, 0);
            }
        }
    }
    #pragma unroll
    for (int fn = 0; fn < 4; ++fn) {
        int o = o0 + wn * 64 + fn * 16 + lrow;
        float mx = 0.0f;   // relu floor
        if (o < COUT) {
            float bv = bias[o];
            #pragma unroll
            for (int fm = 0; fm < 4; ++fm)
                #pragma unroll
                for (int i = 0; i < 4; ++i) {
                    int p = p0 + wm * 64 + fm * 16 + lk * 4 + i;
                    if (p < LOUT) mx = fmaxf(mx, acc[fm][fn][i] + bv);
                }
        }
        mx = fmaxf(mx, __shfl_xor(mx, 16));
        mx = fmaxf(mx, __shfl_xor(mx, 32));
        if (lane < 16 && o < COUT)
            atomicMax((int*)&feats[(size_t)b * 800 + foff + o], __float_as_int(mx));
    }
}

// ================= CSR build =================
__global__ void hist_kernel(const int* __restrict__ dst, int* __restrict__ deg)
{
    int e = blockIdx.x * 256 + threadIdx.x;
    if (e < NEDGE) atomicAdd(&deg[dst[e]], 1);
}

__global__ void scan_kernel(const int* __restrict__ deg, int* __restrict__ off, int* __restrict__ cur)
{
    __shared__ int part[1024];
    const int tid = threadIdx.x;
    const int CH = (NNODE + 1023) / 1024;
    int base = tid * CH;
    int s = 0;
    for (int i = 0; i < CH; ++i) { int idx = base + i; s += (idx < NNODE ? deg[idx] : 0); }
    part[tid] = s;
    __syncthreads();
    for (int d = 1; d < 1024; d <<= 1) {
        int v = (tid >= d) ? part[tid - d] : 0;
        __syncthreads();
        part[tid] += v;
        __syncthreads();
    }
    int run = tid ? part[tid - 1] : 0;
    for (int i = 0; i < CH; ++i) {
        int idx = base + i;
        if (idx < NNODE) { off[idx] = run; cur[idx] = run; run += deg[idx]; }
    }
    if (tid == 1023) off[NNODE] = run;
}

__global__ void fill_kernel(const int* __restrict__ src, const int* __restrict__ dst,
                            int* __restrict__ cur, int* __restrict__ eidx)
{
    int e = blockIdx.x * 256 + threadIdx.x;
    if (e >= NEDGE) return;
    int d = dst[e];
    int pos = atomicAdd(&cur[d], 1);
    eidx[pos] = src[e];
}

// ================= per-layer kernels =================
__global__ void gather_h2(const int* __restrict__ off, const int* __restrict__ eidx,
                          unsigned short* __restrict__ acat)
{
    int t = blockIdx.x * 256 + threadIdx.x;
    if (t >= NNODE * 32) return;
    int c8 = t & 31, n = t >> 5;
    if (c8 >= 25) return;
    const size_t cb = (size_t)c8 * 8;
    float s[8] = {0.f, 0.f, 0.f, 0.f, 0.f, 0.f, 0.f, 0.f};
    int beg = off[n], end = off[n + 1];
    int i = beg;
    for (; i + 4 <= end; i += 4) {
        int s0 = eidx[i], s1 = eidx[i + 1], s2 = eidx[i + 2], s3 = eidx[i + 3];
        ushort8 a = *(const ushort8*)(acat + (size_t)s0 * KP + HOFF + cb);
        ushort8 b = *(const ushort8*)(acat + (size_t)s1 * KP + HOFF + cb);
        ushort8 c = *(const ushort8*)(acat + (size_t)s2 * KP + HOFF + cb);
        ushort8 d = *(const ushort8*)(acat + (size_t)s3 * KP + HOFF + cb);
        #pragma unroll
        for (int j = 0; j < 8; ++j)
            s[j] += (h2f(a[j]) + h2f(b[j])) + (h2f(c[j]) + h2f(d[j]));
    }
    for (; i < end; ++i) {
        int sn = eidx[i];
        ushort8 hh = *(const ushort8*)(acat + (size_t)sn * KP + HOFF + cb);
        #pragma unroll
        for (int j = 0; j < 8; ++j) s[j] += h2f(hh[j]);
    }
    ushort8 o;
    #pragma unroll
    for (int j = 0; j < 8; ++j) o[j] = f2h(s[j]);
    *(ushort8*)(acat + (size_t)n * KP + cb) = o;
}

__global__ void h0_kernel(const float* __restrict__ x, unsigned short* __restrict__ acat)
{
    int t = blockIdx.x * 256 + threadIdx.x;
    if (t >= NNODE * 32) return;
    int c8 = t & 31, n = t >> 5;
    if (c8 >= 28) return;
    ushort8 o = {0,0,0,0,0,0,0,0};
    if (c8 < 25) {
        const float* src = x + (size_t)n * H + c8 * 8;
        float4v v0 = *(const float4v*)src;
        float4v v1 = *(const float4v*)(src + 4);
        o[0] = f2h(v0[0]); o[1] = f2h(v0[1]); o[2] = f2h(v0[2]); o[3] = f2h(v0[3]);
        o[4] = f2h(v1[0]); o[5] = f2h(v1[1]); o[6] = f2h(v1[2]); o[7] = f2h(v1[3]);
    }
    *(ushort8*)(acat + (size_t)n * KP + HOFF + c8 * 8) = o;
}

// ================= weight prep (gate-permuted) =================
__global__ void wih16p_prep(const float* __restrict__ wih, unsigned short* __restrict__ w16)
{
    int t = blockIdx.x * 256 + threadIdx.x;
    if (t >= 896 * 32) return;
    int c8 = t & 31, r = t >> 5;
    int g = (r >> 4) & 3;
    int c = (r >> 6) * 16 + (r & 15);
    ushort8 o = {0,0,0,0,0,0,0,0};
    if (g < 3 && c < H) {
        #pragma unroll
        for (int j = 0; j < 8; ++j) {
            int k = c8 * 8 + j;
            if (k < H) o[j] = f2h(wih[(size_t)(g * 200 + c) * H + k]);
        }
    }
    *(ushort8*)(w16 + (size_t)r * 256 + c8 * 8) = o;
}

__global__ void wl_prep(const float* __restrict__ w, unsigned short* __restrict__ wl)
{
    int t = blockIdx.x * 256 + threadIdx.x;
    if (t >= NLAY * 256 * 32) return;
    int c8 = t & 31;
    int rest = t >> 5;
    int jr = rest & 255;
    int l = rest >> 8;
    ushort8 o = {0,0,0,0,0,0,0,0};
    if (jr < H) {
        #pragma unroll
        for (int j = 0; j < 8; ++j) {
            int k = c8 * 8 + j;
            if (k < H) o[j] = f2h(w[(size_t)l * H * H + (size_t)jr * H + k]);
        }
    }
    *(ushort8*)(wl + (size_t)l * 65536 + (size_t)jr * 256 + c8 * 8) = o;
}

// right half (K-cols 224..447) of permuted Wf[l][896][448]; also permuted bias bb[896]
__global__ void wf_rightp(const float* __restrict__ whh, const float* __restrict__ bih,
                          const float* __restrict__ bhh,
                          unsigned short* __restrict__ Wf, float* __restrict__ bb)
{
    int t = blockIdx.x * 256 + threadIdx.x;
    if (t >= NLAY * 896 * 28) return;
    int c8 = t % 28;
    int rest = t / 28;
    int r = rest % 896;
    int l = rest / 896;
    int g = (r >> 4) & 3;
    int c = (r >> 6) * 16 + (r & 15);
    ushort8 o = {0,0,0,0,0,0,0,0};
    if (c < H) {
        #pragma unroll
        for (int j = 0; j < 8; ++j) {
            int kk = c8 * 8 + j;
            float v = 0.0f;
            if (kk < H) {
                if (g == 0)      v = whh[(size_t)c * H + kk];
                else if (g == 1) v = whh[(size_t)(200 + c) * H + kk];
                else if (g == 3) v = whh[(size_t)(400 + c) * H + kk];
            }
            o[j] = f2h(v);
        }
    }
    *(ushort8*)(Wf + (size_t)l * (896 * KP) + (size_t)r * KP + HOFF + c8 * 8) = o;
    if (l == 0 && c8 == 0) {
        float bv = 0.0f;
        if (c < H) {
            if (g == 0)      bv = bih[c] + bhh[c];
            else if (g == 1) bv = bih[200 + c] + bhh[200 + c];
            else if (g == 2) bv = bih[400 + c];
            else             bv = bhh[400 + c];
        }
        bb[r] = bv;
    }
}

// ================= conv-phase prep =================
__global__ void embed_bf16_kernel(const int* __restrict__ ids, const float* __restrict__ table,
                                  unsigned short* __restrict__ e)
{
    int t = blockIdx.x * 256 + threadIdx.x;
    const int total = NB * SEQ * (EMBD / 8);
    if (t >= total) return;
    int j = t % (EMBD / 8), row = t / (EMBD / 8);
    int id = ids[row];
    const float* src = table + (size_t)id * EMBD + j * 8;
    float4v v0 = *(const float4v*)src;
    float4v v1 = *(const float4v*)(src + 4);
    ushort8 o;
    o[0] = f2bf(v0[0]); o[1] = f2bf(v0[1]); o[2] = f2bf(v0[2]); o[3] = f2bf(v0[3]);
    o[4] = f2bf(v1[0]); o[5] = f2bf(v1[1]); o[6] = f2bf(v1[2]); o[7] = f2bf(v1[3]);
    *(ushort8*)(e + (size_t)row * EMBD + j * 8) = o;
}

__global__ void h_pad_from_acat(const unsigned short* __restrict__ acat,
                                unsigned short* __restrict__ e0)
{
    int t = blockIdx.x * 256 + threadIdx.x;
    const int total = NB * 208 * 32;
    if (t >= total) return;
    int c8 = t % 32, rest = t / 32;
    int r = rest % 208, b = rest / 208;
    ushort8 o = {0,0,0,0,0,0,0,0};
    if (r >= 1 && r <= 205 && c8 < 25) {
        int node = b * NPER + (r - 1);
        ushort8 hh = *(const ushort8*)(acat + (size_t)node * KP + HOFF + c8 * 8);
        #pragma unroll
        for (int j = 0; j < 8; ++j) o[j] = f2bf(h2f(hh[j]));
    }
    *(ushort8*)(e0 + ((size_t)(b * 208 + r)) * 256 + c8 * 8) = o;
}

__global__ void wconv_bf16_kernel(const float* __restrict__ w, unsigned short* __restrict__ wt,
                                  int K, int CINP, int CINR, int COUT)
{
    long long t = (long long)blockIdx.x * 256 + threadIdx.x;
    long long total = (long long)K * 256 * CINP;
    if (t >= total) return;
    int cin = (int)(t % CINP);
    long long rest = t / CINP;
    int o = (int)(rest % 256), k = (int)(rest / 256);
    float v = 0.0f;
    if (o < COUT && cin < CINR) v = w[((size_t)o * CINR + cin) * K + k];
    wt[t] = f2bf(v);
}

__global__ __launch_bounds__(256)
void fc_head(const float* __restrict__ feats,
             const float* __restrict__ w1, const float* __restrict__ b1,
             const float* __restrict__ w2, const float* __restrict__ b2,
             const float* __restrict__ w3, const float* __restrict__ b3,
             float* __restrict__ out)
{
    __shared__ float f[800];
    __shared__ float h1[256];
    __shared__ float h2[128];
    const int b = blockIdx.x, tid = threadIdx.x;
    for (int i = tid; i < 800; i += 256) f[i] = feats[(size_t)b * 800 + i];
    __syncthreads();
    {
        float acc = b1[tid];
        const float* wr = w1 + (size_t)tid * 800;
        for (int k = 0; k < 800; ++k) acc = fmaf(f[k], wr[k], acc);
        h1[tid] = fmaxf(acc, 0.0f);
    }
    __syncthreads();
    if (tid < 128) {
        float acc = b2[tid];
        const float* wr = w2 + (size_t)tid * 256;
        for (int k = 0; k < 256; ++k) acc = fmaf(h1[k], wr[k], acc);
        h2[tid] = fmaxf(acc, 0.0f);
    }
    __syncthreads();
    if (tid < 2) {
        float acc = b3[tid];
        const float* wr = w3 + (size_t)tid * 128;
        for (int k = 0; k < 128; ++k) acc = fmaf(h2[k], wr[k], acc);
        out[(size_t)b * 2 + tid] = acc;
    }
}

} // namespace

extern "C" void kernel_launch(void* const* d_in, const int* in_sizes, int n_in,
                              void* d_out, int out_size, void* d_ws, size_t ws_size,
                              hipStream_t stream)
{
    const float* x         = (const float*)d_in[0];
    const int*   edge      = (const int*)d_in[1];
    const int*   input_ids = (const int*)d_in[2];
    const float* table     = (const float*)d_in[3];
    const float* ggc_w     = (const float*)d_in[4];
    const float* wih       = (const float*)d_in[5];
    const float* whh       = (const float*)d_in[6];
    const float* bih       = (const float*)d_in[7];
    const float* bhh       = (const float*)d_in[8];
    const float* c0w = (const float*)d_in[9];  const float* c0b = (const float*)d_in[10];
    const float* c1w = (const float*)d_in[11]; const float* c1b = (const float*)d_in[12];
    const float* c2w = (const float*)d_in[13]; const float* c2b = (const float*)d_in[14];
    const float* c3w = (const float*)d_in[15]; const float* c3b = (const float*)d_in[16];
    const float* f1w = (const float*)d_in[17]; const float* f1b = (const float*)d_in[18];
    const float* f2w = (const float*)d_in[19]; const float* f2b = (const float*)d_in[20];
    const float* f3w = (const float*)d_in[21]; const float* f3b = (const float*)d_in[22];
    float* out = (float*)d_out;

    // ---- workspace layout (float-slot offsets) ----
    float* ws = (float*)d_ws;
    unsigned short* acat_a = (unsigned short*)(ws + 0);          // 26240*448 ush
    unsigned short* acat_b = (unsigned short*)(ws + 5877760);    // 26240*448 ush
    unsigned short* Wf     = (unsigned short*)(ws + 11755520);   // 6*896*448 ush
    unsigned short* wl16   = (unsigned short*)(ws + 12959744);   // 6*256*256 ush
    unsigned short* wih16p = (unsigned short*)(ws + 13156352);   // 896*256 ush
    float* b_big = ws + 13271040;                                // 896
    int* deg  = (int*)(ws + 13271936);                           // 26240
    int* off  = (int*)(ws + 13298176);                           // 26241
    int* cur  = (int*)(ws + 13324417);                           // 26241
    int* eidx = (int*)(ws + 13350658);                           // 209920
    // conv-phase aliases (all GGC buffers dead by then):
    unsigned short* e_bf16 = (unsigned short*)(ws + 0);          // 128*512*768 ush
    unsigned short* e0     = (unsigned short*)(ws + 25165824);   // 128*208*256 ush
    unsigned short* wt0    = (unsigned short*)(ws + 28600000);
    unsigned short* wt1    = wt0 + (size_t)3 * 256 * 256;
    unsigned short* wt2    = wt1 + (size_t)3 * 256 * EMBD;
    unsigned short* wt3    = wt2 + (size_t)4 * 256 * EMBD;
    float* feats = ws + 29900000;                                // 128*800

    const int* srcp = edge;
    const int* dstp = edge + NEDGE;

    dim3 blk(256);
    dim3 blk512(512);

    // ---- one-time prep ----
    hipMemsetAsync(deg, 0, sizeof(int) * NNODE, stream);
    hist_kernel<<<dim3((NEDGE + 255) / 256), blk, 0, stream>>>(dstp, deg);
    scan_kernel<<<dim3(1), dim3(1024), 0, stream>>>(deg, off, cur);
    fill_kernel<<<dim3((NEDGE + 255) / 256), blk, 0, stream>>>(srcp, dstp, cur, eidx);
    h0_kernel<<<dim3((NNODE * 32 + 255) / 256), blk, 0, stream>>>(x, acat_a);
    wih16p_prep<<<dim3((896 * 32 + 255) / 256), blk, 0, stream>>>(wih, wih16p);
    wl_prep<<<dim3((NLAY * 256 * 32 + 255) / 256), blk, 0, stream>>>(ggc_w, wl16);
    hipMemsetAsync(Wf, 0, (size_t)NLAY * 896 * KP * 2, stream);
    wf_rightp<<<dim3((NLAY * 896 * 28 + 255) / 256), blk, 0, stream>>>(whh, bih, bhh, Wf, b_big);
    // Wf left (K-cols 0..199) = wih_perm @ W_l^T, batched over layers via z
    gemm_w64<false, true><<<dim3(7, 2, NLAY), blk, 0, stream>>>(
        wih16p, 256, wl16, (size_t)256 * 256, nullptr, 896, 200,
        nullptr, Wf, (size_t)896 * KP, KP, 256);

    // ---- GGC layers: gather + fused gate-GEMM/GRU (ping-pong acat) ----
    unsigned short* bufs[2] = { acat_a, acat_b };
    for (int l = 0; l < NLAY; ++l) {
        unsigned short* curb = bufs[l & 1];
        unsigned short* nxtb = bufs[(l + 1) & 1];
        gather_h2<<<dim3((NNODE * 32 + 255) / 256), blk, 0, stream>>>(off, eidx, curb);
        gemm_gru<<<dim3(NNODE / 128, 7), blk, 0, stream>>>(
            curb, Wf + (size_t)l * (896 * KP), b_big, nxtb);
    }
    // after 6 layers, h lives in bufs[0] = acat_a

    // ---- conv phase ----
    h_pad_from_acat<<<dim3((NB * 208 * 32 + 255) / 256), blk, 0, stream>>>(acat_a, e0);
    embed_bf16_kernel<<<dim3(NB * SEQ * (EMBD / 8) / 256), blk, 0, stream>>>(input_ids, table, e_bf16);
    wconv_bf16_kernel<<<dim3((3 * 256 * 256 + 255) / 256), blk, 0, stream>>>(c0w, wt0, 3, 256, 200, 200);
    wconv_bf16_kernel<<<dim3((3 * 256 * EMBD + 255) / 256), blk, 0, stream>>>(c1w, wt1, 3, EMBD, EMBD, 200);
    wconv_bf16_kernel<<<dim3((4 * 256 * EMBD + 255) / 256), blk, 0, stream>>>(c2w, wt2, 4, EMBD, EMBD, 200);
    wconv_bf16_kernel<<<dim3((5 * 256 * EMBD + 255) / 256), blk, 0, stream>>>(c3w, wt3, 5, EMBD, EMBD, 200);

    hipMemsetAsync(feats, 0, sizeof(float) * NB * 800, stream);
    conv_w64<3, 256, 208, 205><<<dim3(1, 2, NB), blk512, 0, stream>>>(e0, wt0, c0b, 200, feats, 0);
    conv_w64<3, EMBD, SEQ, 510><<<dim3(2, 2, NB), blk512, 0, stream>>>(e_bf16, wt1, c1b, 200, feats, 200);
    conv_w64<4, EMBD, SEQ, 509><<<dim3(2, 2, NB), blk512, 0, stream>>>(e_bf16, wt2, c2b, 200, feats, 400);
    conv_w64<5, EMBD, SEQ, 508><<<dim3(2, 2, NB), blk512, 0, stream>>>(e_bf16, wt3, c3b, 200, feats, 600);

    fc_head<<<dim3(NB), blk, 0, stream>>>(feats, f1w, f1b, f2w, f2b, f3w, f3b, out);
}